// Round 8
// baseline (517.342 us; speedup 1.0000x reference)
//
#include <hip/hip_runtime.h>

// VQ: N=262144 vectors (64x4096), D=64, K=512 codewords, fp32.
// out (float32): quantized[16777216] | indices[262144] (as float) | loss[1]
//
// R8: move the 512-way scan onto the MFMA pipe (idle all previous rounds).
// fp16 two-term split: x = hi+lo, dot ~= hi*hi + lo*hi + hi*lo via
// mfma_f32_16x16x32_f16 (6 MFMAs / 16x16 tile, K'=192). |err| <~ 1e-2;
// rows whose best-vs-runner-up margin (in D = dot - csq/2 domain) is
// < DMARGIN get an exact fp32 rescan (fixup kernel). Correctness does NOT
// depend on the error bound — only the fixup fraction does.
// Layout conventions (HW-verified per guide m89/m120):
//   A-frag: A[m=lane&15][k=quad*8+j]; B-frag: B[n=lane&15][k=quad*8+j];
//   C/D:    col=lane&15, row=quad*4+reg.

typedef _Float16 half8 __attribute__((ext_vector_type(8)));
typedef float    floatx4 __attribute__((ext_vector_type(4)));

#define NVEC  262144
#define DDIM  64
#define KCW   512
#define LOSS_SCALE (0.25f / 16777216.0f)
#define DMARGIN 0.075f
// ws layout: csq fp32[512] @ 0 ; flags u8[NVEC] @ 2048

__global__ void prep_kernel(const float* __restrict__ cw,
                            float* __restrict__ csq,
                            float* __restrict__ loss_slot) {
    int n = blockIdx.x * blockDim.x + threadIdx.x;
    if (n < KCW) {
        const float4* r = (const float4*)(cw + n * DDIM);
        float s = 0.f;
        #pragma unroll
        for (int t = 0; t < 16; ++t) {
            float4 v = r[t];
            s += v.x * v.x + v.y * v.y + v.z * v.z + v.w * v.w;
        }
        csq[n] = s;
    }
    if (n == 0) *loss_slot = 0.f;   // d_out poisoned before every launch
}

__device__ __forceinline__ float untrans(unsigned u) {
    unsigned b = (u & 0x80000000u) ? (u ^ 0x80000000u) : ~u;
    return __uint_as_float(b);
}

__global__ __launch_bounds__(256, 2)
void vq_mfma_kernel(const float* __restrict__ x, const float* __restrict__ cw,
                    const float* __restrict__ csq_ws,
                    unsigned char* __restrict__ flags,
                    float* __restrict__ out_q, float* __restrict__ out_idx,
                    float* __restrict__ out_loss) {
    __shared__ _Float16 Bs[128 * 136];   // 34 KB: [n_local][hi(64)|lo(64)], pad to 136
    __shared__ float csqs[KCW];          // 2 KB
    __shared__ int   win[256];
    __shared__ unsigned char flg[256];
    __shared__ float red[4];

    const int tid  = threadIdx.x;
    const int w    = tid >> 6;
    const int lane = tid & 63;
    const int quad = lane >> 4;
    const int col  = lane & 15;
    const long blk   = (long)blockIdx.x * 256;
    const long wbase = blk + w * 64;

    csqs[tid]       = csq_ws[tid];
    csqs[tid + 256] = csq_ws[tid + 256];

    // ---- a-frags: 4 row-tiles, hi/lo split, register-resident (64 VGPRs) ----
    half8 ah0[4], ah1[4], al0[4], al1[4];
    #pragma unroll
    for (int rt = 0; rt < 4; ++rt) {
        const float* xr = x + (wbase + rt * 16 + col) * DDIM;
        float4 f0 = *(const float4*)(xr + quad * 8);
        float4 f1 = *(const float4*)(xr + quad * 8 + 4);
        float4 g0 = *(const float4*)(xr + 32 + quad * 8);
        float4 g1 = *(const float4*)(xr + 32 + quad * 8 + 4);
        const float* fp = (const float*)&f0;   // f0,f1 contiguous? no — handle separately
        #pragma unroll
        for (int i = 0; i < 4; ++i) {
            float v = ((const float*)&f0)[i];
            _Float16 h = (_Float16)v;
            ah0[rt][i] = h; al0[rt][i] = (_Float16)(v - (float)h);
            v = ((const float*)&f1)[i]; h = (_Float16)v;
            ah0[rt][4 + i] = h; al0[rt][4 + i] = (_Float16)(v - (float)h);
            v = ((const float*)&g0)[i]; h = (_Float16)v;
            ah1[rt][i] = h; al1[rt][i] = (_Float16)(v - (float)h);
            v = ((const float*)&g1)[i]; h = (_Float16)v;
            ah1[rt][4 + i] = h; al1[rt][4 + i] = (_Float16)(v - (float)h);
        }
        (void)fp;
    }

    unsigned best[16], best2[16];
    #pragma unroll
    for (int s = 0; s < 16; ++s) { best[s] = 0u; best2[s] = 0u; }

    for (int ch = 0; ch < 4; ++ch) {
        __syncthreads();   // prior chunk consumed (first iter: covers csqs)
        // ---- stage + split 128 codewords into LDS ----
        {
            int nl = tid >> 1, h = tid & 1;
            const float* g = cw + (ch * 128 + nl) * DDIM + h * 32;
            _Float16* hb = &Bs[nl * 136 + h * 32];
            _Float16* lb = &Bs[nl * 136 + 64 + h * 32];
            #pragma unroll
            for (int b = 0; b < 4; ++b) {
                float4 va = *(const float4*)(g + 8 * b);
                float4 vb = *(const float4*)(g + 8 * b + 4);
                half8 hh, ll;
                #pragma unroll
                for (int i = 0; i < 4; ++i) {
                    float v = ((const float*)&va)[i];
                    _Float16 hv = (_Float16)v;
                    hh[i] = hv; ll[i] = (_Float16)(v - (float)hv);
                    v = ((const float*)&vb)[i]; hv = (_Float16)v;
                    hh[4 + i] = hv; ll[4 + i] = (_Float16)(v - (float)hv);
                }
                *(half8*)(hb + 8 * b) = hh;
                *(half8*)(lb + 8 * b) = ll;
            }
        }
        __syncthreads();

        for (int t = 0; t < 8; ++t) {
            const int n = ch * 128 + t * 16 + col;
            const int nb = (t * 16 + col) * 136;
            half8 bh0 = *(const half8*)&Bs[nb + quad * 8];
            half8 bh1 = *(const half8*)&Bs[nb + 32 + quad * 8];
            half8 bl0 = *(const half8*)&Bs[nb + 64 + quad * 8];
            half8 bl1 = *(const half8*)&Bs[nb + 96 + quad * 8];
            const float csqh = 0.5f * csqs[n];
            const unsigned inv = 511u - (unsigned)n;

            #pragma unroll
            for (int rt = 0; rt < 4; ++rt) {
                floatx4 acc = {0.f, 0.f, 0.f, 0.f};
                acc = __builtin_amdgcn_mfma_f32_16x16x32_f16(ah0[rt], bh0, acc, 0, 0, 0);
                acc = __builtin_amdgcn_mfma_f32_16x16x32_f16(ah1[rt], bh1, acc, 0, 0, 0);
                acc = __builtin_amdgcn_mfma_f32_16x16x32_f16(al0[rt], bh0, acc, 0, 0, 0);
                acc = __builtin_amdgcn_mfma_f32_16x16x32_f16(al1[rt], bh1, acc, 0, 0, 0);
                acc = __builtin_amdgcn_mfma_f32_16x16x32_f16(ah0[rt], bl0, acc, 0, 0, 0);
                acc = __builtin_amdgcn_mfma_f32_16x16x32_f16(ah1[rt], bl1, acc, 0, 0, 0);
                #pragma unroll
                for (int reg = 0; reg < 4; ++reg) {
                    float Dv = acc[reg] - csqh;       // maximize D
                    unsigned b = __float_as_uint(Dv);
                    unsigned u = b ^ ((unsigned)((int)b >> 31) | 0x80000000u);
                    unsigned key = (u & 0xFFFFFE00u) | inv;   // tie -> smaller n
                    int s = rt * 4 + reg;
                    unsigned mn = best[s] < key ? best[s] : key;
                    best[s]  = best[s] > key ? best[s] : key;
                    best2[s] = best2[s] > mn ? best2[s] : mn;
                }
            }
        }
    }

    // ---- cross-lane (best, best2) reduce over the 16 cols of each quad ----
    #pragma unroll
    for (int off = 1; off < 16; off <<= 1) {
        #pragma unroll
        for (int s = 0; s < 16; ++s) {
            unsigned ob  = (unsigned)__shfl_xor((int)best[s],  off, 16);
            unsigned ob2 = (unsigned)__shfl_xor((int)best2[s], off, 16);
            unsigned mn = best[s] < ob ? best[s] : ob;
            best[s]  = best[s] > ob ? best[s] : ob;
            unsigned m2 = best2[s] > ob2 ? best2[s] : ob2;
            best2[s] = m2 > mn ? m2 : mn;
        }
    }
    if (col < 4) {   // lane col handles reg=col for all 4 row-tiles
        #pragma unroll
        for (int rt = 0; rt < 4; ++rt) {
            int s = rt * 4 + col;
            unsigned bk = best[s], b2 = best2[s];
            int n_win = 511 - (int)(bk & 511u);
            float D1 = untrans(bk & 0xFFFFFE00u);
            float D2 = untrans(b2 & 0xFFFFFE00u);
            int f = (D1 - D2 <= DMARGIN) ? 1 : 0;
            long row = wbase + rt * 16 + quad * 4 + col;
            int rl = (int)(row - blk);
            win[rl] = n_win;
            flg[rl] = (unsigned char)f;
            flags[row] = (unsigned char)f;
            out_idx[row] = (float)n_win;
        }
    }
    __syncthreads();

    // ---- quantized write + commitment loss (skip flagged rows' loss) ----
    float ls = 0.f;
    #pragma unroll
    for (int p = 0; p < 2; ++p) {
        int m = p * 128 + (tid >> 1), h = tid & 1;
        int wn = win[m];
        int f  = flg[m];
        const float4* qg = (const float4*)(cw + wn * DDIM + h * 32);  // L2-hot
        const float4* xg = (const float4*)(x + (blk + m) * DDIM + h * 32);
        float4* og = (float4*)(out_q + (blk + m) * DDIM + h * 32);
        #pragma unroll
        for (int t = 0; t < 8; ++t) {
            float4 q = qg[t];
            float4 xv = xg[t];
            og[t] = q;
            if (!f) {
                float d0 = q.x - xv.x, d1 = q.y - xv.y;
                float d2 = q.z - xv.z, d3 = q.w - xv.w;
                ls += d0 * d0 + d1 * d1 + d2 * d2 + d3 * d3;
            }
        }
    }
    #pragma unroll
    for (int off = 32; off > 0; off >>= 1) ls += __shfl_down(ls, off, 64);
    if ((tid & 63) == 0) red[tid >> 6] = ls;
    __syncthreads();
    if (tid == 0)
        atomicAdd(out_loss, ((red[0] + red[1]) + (red[2] + red[3])) * LOSS_SCALE);
}

// Exact fp32 rescan for flagged rows. 16 lanes per row, R4's verified
// formula family (expansion form, 4-chain fma) and first-min tie-break.
__global__ __launch_bounds__(256, 4)
void fixup_kernel(const float* __restrict__ x, const float* __restrict__ cw,
                  const float* __restrict__ csq_ws,
                  const unsigned char* __restrict__ flags,
                  float* __restrict__ out_q, float* __restrict__ out_idx,
                  float* __restrict__ out_loss) {
    const int tid = threadIdx.x;
    const int grp = tid >> 4;
    const int tx  = tid & 15;
    for (int it = 0; it < 8; ++it) {
        long row = ((long)it * 2048 + blockIdx.x) * 16 + grp;
        if (!flags[row]) continue;

        float4 xr[16];
        const float4* xg = (const float4*)(x + row * DDIM);
        #pragma unroll
        for (int t = 0; t < 16; ++t) xr[t] = xg[t];

        float best = 3.402823466e38f; int bi = 0;
        for (int j = 0; j < 32; ++j) {
            int n = tx + 16 * j;                 // ascending per lane
            const float4* c = (const float4*)(cw + n * DDIM);
            float a0 = 0.f, a1 = 0.f, a2 = 0.f, a3 = 0.f;
            #pragma unroll
            for (int t = 0; t < 16; ++t) {
                float4 cv = c[t];
                a0 = __builtin_fmaf(xr[t].x, cv.x, a0);
                a1 = __builtin_fmaf(xr[t].y, cv.y, a1);
                a2 = __builtin_fmaf(xr[t].z, cv.z, a2);
                a3 = __builtin_fmaf(xr[t].w, cv.w, a3);
            }
            float sc = __builtin_fmaf(-2.f, (a0 + a1) + (a2 + a3), csq_ws[n]);
            if (sc < best) { best = sc; bi = n; }
        }
        #pragma unroll
        for (int off = 8; off > 0; off >>= 1) {
            float d2 = __shfl_down(best, off, 16);
            int   i2 = __shfl_down(bi,   off, 16);
            if (d2 < best || (d2 == best && i2 < bi)) { best = d2; bi = i2; }
        }
        if (tx == 0) {
            out_idx[row] = (float)bi;
            const float4* qg = (const float4*)(cw + bi * DDIM);
            float4* og = (float4*)(out_q + row * DDIM);
            float ls = 0.f;
            #pragma unroll
            for (int t = 0; t < 16; ++t) {
                float4 q = qg[t];
                og[t] = q;
                float d0 = q.x - xr[t].x, d1 = q.y - xr[t].y;
                float d2_ = q.z - xr[t].z, d3 = q.w - xr[t].w;
                ls += d0 * d0 + d1 * d1 + d2_ * d2_ + d3 * d3;
            }
            atomicAdd(out_loss, ls * LOSS_SCALE);
        }
    }
}

extern "C" void kernel_launch(void* const* d_in, const int* in_sizes, int n_in,
                              void* d_out, int out_size, void* d_ws, size_t ws_size,
                              hipStream_t stream) {
    const float* x  = (const float*)d_in[0];   // (64,4096,64) fp32
    const float* cw = (const float*)d_in[1];   // (512,64) fp32
    float* out      = (float*)d_out;
    float* out_q    = out;                      // 16777216
    float* out_idx  = out + 16777216;           // 262144
    float* out_loss = out + 16777216 + 262144;  // 1
    float* csq      = (float*)d_ws;                            // 2 KB
    unsigned char* flags = (unsigned char*)d_ws + 2048;        // 256 KB

    prep_kernel<<<8, 64, 0, stream>>>(cw, csq, out_loss);
    vq_mfma_kernel<<<NVEC / 256, 256, 0, stream>>>(x, cw, csq, flags,
                                                   out_q, out_idx, out_loss);
    fixup_kernel<<<2048, 256, 0, stream>>>(x, cw, csq, flags,
                                           out_q, out_idx, out_loss);
}

// Round 9
// 305.365 us; speedup vs baseline: 1.6942x; 1.6942x over previous
//
#include <hip/hip_runtime.h>

// VQ: N=262144 vectors (64x4096), D=64, K=512 codewords, fp32.
// out (float32): quantized[16777216] | indices[262144] (as float) | loss[1]
//
// R9 = R8 (verified-correct MFMA fp16-split path) with the overhead removed:
//  - codeword hi/lo split precomputed ONCE in prep (d_ws), not per chunk
//  - 6-op float score update (v = csq/2 - dot; min/max + cmp/cndmask idx)
//    instead of 9-op integer-key transform; full precision, exact ties
//  - DMARGIN 0.075 -> 0.015 (error bound ~1.5e-4; 100x headroom)
//  - flagged rows compacted into a dense list; fixup iterates the list only
// Layout conventions (HW-verified, R8 passed absmax 0):
//   A-frag: A[m=lane&15][k=quad*8+j]; B-frag: B[n=lane&15][k=quad*8+j];
//   C/D:    col=lane&15, row=quad*4+reg.

typedef _Float16 half8 __attribute__((ext_vector_type(8)));
typedef float    floatx4 __attribute__((ext_vector_type(4)));

#define NVEC  262144
#define DDIM  64
#define KCW   512
#define LOSS_SCALE (0.25f / 16777216.0f)
#define DMARGIN 0.015f
#define FIX_BLOCKS 128

// d_ws layout (re-poisoned 0xAA every call -> prep rewrites everything):
#define WS_CSQ   0          // f32[512]
#define WS_CSQH  2048       // f32[512]  (0.5*csq)
#define WS_CTR   4096       // unsigned[1]
#define WS_HL    8192       // f16[512*128]: row n = hi[64] | lo[64] (256 B)
#define WS_LIST  139264     // int[61440]
#define LIST_CAP 61440

__global__ void prep_kernel(const float* __restrict__ cw,
                            float* __restrict__ csq,
                            float* __restrict__ csqh,
                            _Float16* __restrict__ cw_hl,
                            unsigned* __restrict__ ctr,
                            float* __restrict__ loss_slot) {
    int n = blockIdx.x * blockDim.x + threadIdx.x;
    if (n < KCW) {
        const float4* r = (const float4*)(cw + n * DDIM);
        _Float16* orow = cw_hl + n * 128;
        float s = 0.f;
        #pragma unroll
        for (int t = 0; t < 8; ++t) {
            float4 a = r[2 * t], b = r[2 * t + 1];
            half8 hh, ll;
            #pragma unroll
            for (int i = 0; i < 4; ++i) {
                float v = ((const float*)&a)[i];
                s += v * v;
                _Float16 h = (_Float16)v;
                hh[i] = h; ll[i] = (_Float16)(v - (float)h);
                v = ((const float*)&b)[i];
                s += v * v;
                h = (_Float16)v;
                hh[4 + i] = h; ll[4 + i] = (_Float16)(v - (float)h);
            }
            *(half8*)(orow + 8 * t) = hh;
            *(half8*)(orow + 64 + 8 * t) = ll;
        }
        csq[n]  = s;
        csqh[n] = 0.5f * s;
    }
    if (n == 0) { *loss_slot = 0.f; *ctr = 0u; }
}

__global__ __launch_bounds__(256, 2)
void vq_mfma_kernel(const float* __restrict__ x, const float* __restrict__ cw,
                    const _Float16* __restrict__ cw_hl,
                    const float* __restrict__ csqh,
                    unsigned* __restrict__ ctr, int* __restrict__ list,
                    float* __restrict__ out_q, float* __restrict__ out_idx,
                    float* __restrict__ out_loss) {
    __shared__ _Float16 Bs[128 * 136];   // 34 KB: [n_local][hi64|lo64], pad 136
    __shared__ float csqhs[KCW];         // 2 KB
    __shared__ int   win[256];
    __shared__ unsigned char flg[256];
    __shared__ float red[4];

    const int tid  = threadIdx.x;
    const int w    = tid >> 6;
    const int lane = tid & 63;
    const int quad = lane >> 4;
    const int col  = lane & 15;
    const long blk   = (long)blockIdx.x * 256;
    const long wbase = blk + w * 64;

    csqhs[tid]       = csqh[tid];
    csqhs[tid + 256] = csqh[tid + 256];

    // ---- a-frags: 4 row-tiles, hi/lo split, register-resident ----
    half8 ah0[4], ah1[4], al0[4], al1[4];
    #pragma unroll
    for (int rt = 0; rt < 4; ++rt) {
        const float* xr = x + (wbase + rt * 16 + col) * DDIM;
        float4 f0 = *(const float4*)(xr + quad * 8);
        float4 f1 = *(const float4*)(xr + quad * 8 + 4);
        float4 g0 = *(const float4*)(xr + 32 + quad * 8);
        float4 g1 = *(const float4*)(xr + 32 + quad * 8 + 4);
        #pragma unroll
        for (int i = 0; i < 4; ++i) {
            float v = ((const float*)&f0)[i];
            _Float16 h = (_Float16)v;
            ah0[rt][i] = h; al0[rt][i] = (_Float16)(v - (float)h);
            v = ((const float*)&f1)[i]; h = (_Float16)v;
            ah0[rt][4 + i] = h; al0[rt][4 + i] = (_Float16)(v - (float)h);
            v = ((const float*)&g0)[i]; h = (_Float16)v;
            ah1[rt][i] = h; al1[rt][i] = (_Float16)(v - (float)h);
            v = ((const float*)&g1)[i]; h = (_Float16)v;
            ah1[rt][4 + i] = h; al1[rt][4 + i] = (_Float16)(v - (float)h);
        }
    }

    float m1[16], m2[16];
    int   idx[16];
    #pragma unroll
    for (int s = 0; s < 16; ++s) {
        m1[s] = 3.402823466e38f; m2[s] = 3.402823466e38f; idx[s] = 0;
    }

    for (int ch = 0; ch < 4; ++ch) {
        __syncthreads();   // prior chunk consumed (first iter: covers csqhs)
        // ---- stage pre-split chunk: 32 KB, plain copy ----
        {
            int nl = tid >> 1, h = tid & 1;
            const half8* g = (const half8*)(cw_hl + ((ch * 128 + nl) << 7) + (h << 6));
            half8* dst = (half8*)&Bs[nl * 136 + h * 64];
            #pragma unroll
            for (int b = 0; b < 8; ++b) dst[b] = g[b];
        }
        __syncthreads();

        for (int t = 0; t < 8; ++t) {
            const int n  = ch * 128 + t * 16 + col;
            const int nb = (t * 16 + col) * 136;
            half8 bh0 = *(const half8*)&Bs[nb + quad * 8];
            half8 bh1 = *(const half8*)&Bs[nb + 32 + quad * 8];
            half8 bl0 = *(const half8*)&Bs[nb + 64 + quad * 8];
            half8 bl1 = *(const half8*)&Bs[nb + 96 + quad * 8];
            const float vh = csqhs[n];

            #pragma unroll
            for (int rt = 0; rt < 4; ++rt) {
                floatx4 acc = {0.f, 0.f, 0.f, 0.f};
                acc = __builtin_amdgcn_mfma_f32_16x16x32_f16(ah0[rt], bh0, acc, 0, 0, 0);
                acc = __builtin_amdgcn_mfma_f32_16x16x32_f16(ah1[rt], bh1, acc, 0, 0, 0);
                acc = __builtin_amdgcn_mfma_f32_16x16x32_f16(al0[rt], bh0, acc, 0, 0, 0);
                acc = __builtin_amdgcn_mfma_f32_16x16x32_f16(al1[rt], bh1, acc, 0, 0, 0);
                acc = __builtin_amdgcn_mfma_f32_16x16x32_f16(ah0[rt], bl0, acc, 0, 0, 0);
                acc = __builtin_amdgcn_mfma_f32_16x16x32_f16(ah1[rt], bl1, acc, 0, 0, 0);
                #pragma unroll
                for (int reg = 0; reg < 4; ++reg) {
                    int s = rt * 4 + reg;
                    float v = vh - acc[reg];          // (dist - xsq)/2, monotone
                    if (v < m1[s]) idx[s] = n;        // strict < : first-min kept
                    float mx = fmaxf(m1[s], v);
                    m1[s] = fminf(m1[s], v);
                    m2[s] = fminf(m2[s], mx);
                }
            }
        }
    }

    // ---- cross-lane (m1, idx, m2) reduce over the 16 cols of each quad ----
    #pragma unroll
    for (int off = 1; off < 16; off <<= 1) {
        #pragma unroll
        for (int s = 0; s < 16; ++s) {
            float o1 = __shfl_xor(m1[s], off, 16);
            float o2 = __shfl_xor(m2[s], off, 16);
            int   oi = __shfl_xor(idx[s], off, 16);
            float mx = fmaxf(m1[s], o1);
            m2[s] = fminf(fminf(m2[s], o2), mx);
            if (o1 < m1[s] || (o1 == m1[s] && oi < idx[s])) idx[s] = oi;
            m1[s] = fminf(m1[s], o1);
        }
    }

    if (col < 4) {   // lane col handles reg=col for all 4 row-tiles
        #pragma unroll
        for (int rt = 0; rt < 4; ++rt) {
            int s = rt * 4 + col;
            int n_win = idx[s];
            int f = (m2[s] - m1[s] <= DMARGIN) ? 1 : 0;
            long row = wbase + rt * 16 + quad * 4 + col;
            int rl = (int)(row - blk);
            win[rl] = n_win;
            flg[rl] = (unsigned char)f;
            out_idx[row] = (float)n_win;
            if (f) {
                unsigned slot = atomicAdd(ctr, 1u);
                if (slot < LIST_CAP) list[slot] = (int)row;
            }
        }
    }
    __syncthreads();

    // ---- quantized write + commitment loss (flagged rows' loss -> fixup) ----
    float ls = 0.f;
    #pragma unroll
    for (int p = 0; p < 2; ++p) {
        int m = p * 128 + (tid >> 1), h = tid & 1;
        int wn = win[m];
        int f  = flg[m];
        const float4* qg = (const float4*)(cw + wn * DDIM + h * 32);  // L2-hot
        const float4* xg = (const float4*)(x + (blk + m) * DDIM + h * 32);
        float4* og = (float4*)(out_q + (blk + m) * DDIM + h * 32);
        #pragma unroll
        for (int t = 0; t < 8; ++t) {
            float4 q = qg[t];
            float4 xv = xg[t];
            og[t] = q;
            if (!f) {
                float d0 = q.x - xv.x, d1 = q.y - xv.y;
                float d2 = q.z - xv.z, d3 = q.w - xv.w;
                ls += d0 * d0 + d1 * d1 + d2 * d2 + d3 * d3;
            }
        }
    }
    #pragma unroll
    for (int off = 32; off > 0; off >>= 1) ls += __shfl_down(ls, off, 64);
    if ((tid & 63) == 0) red[tid >> 6] = ls;
    __syncthreads();
    if (tid == 0)
        atomicAdd(out_loss, ((red[0] + red[1]) + (red[2] + red[3])) * LOSS_SCALE);
}

// Exact fp32 rescan over the DENSE flagged-row list (R4's verified formula
// and first-min tie-break; R4+R8 both matched reference with absmax 0).
__global__ __launch_bounds__(256, 4)
void fixup_kernel(const float* __restrict__ x, const float* __restrict__ cw,
                  const float* __restrict__ csq,
                  const unsigned* __restrict__ ctr, const int* __restrict__ list,
                  float* __restrict__ out_q, float* __restrict__ out_idx,
                  float* __restrict__ out_loss) {
    const int tid = threadIdx.x;
    const int grp = tid >> 4;
    const int tx  = tid & 15;
    const int gid = blockIdx.x * 16 + grp;
    unsigned cnt = *ctr;
    const int count = (int)(cnt < LIST_CAP ? cnt : LIST_CAP);

    for (int i = gid; i < count; i += 16 * FIX_BLOCKS) {
        long row = (long)list[i];

        float4 xr[16];
        const float4* xg = (const float4*)(x + row * DDIM);
        #pragma unroll
        for (int t = 0; t < 16; ++t) xr[t] = xg[t];

        float best = 3.402823466e38f; int bi = 0;
        for (int j = 0; j < 32; ++j) {
            int n = tx + 16 * j;                 // ascending per lane
            const float4* c = (const float4*)(cw + n * DDIM);
            float a0 = 0.f, a1 = 0.f, a2 = 0.f, a3 = 0.f;
            #pragma unroll
            for (int t = 0; t < 16; ++t) {
                float4 cv = c[t];
                a0 = __builtin_fmaf(xr[t].x, cv.x, a0);
                a1 = __builtin_fmaf(xr[t].y, cv.y, a1);
                a2 = __builtin_fmaf(xr[t].z, cv.z, a2);
                a3 = __builtin_fmaf(xr[t].w, cv.w, a3);
            }
            float sc = __builtin_fmaf(-2.f, (a0 + a1) + (a2 + a3), csq[n]);
            if (sc < best) { best = sc; bi = n; }
        }
        #pragma unroll
        for (int off = 8; off > 0; off >>= 1) {
            float d2 = __shfl_down(best, off, 16);
            int   i2 = __shfl_down(bi,   off, 16);
            if (d2 < best || (d2 == best && i2 < bi)) { best = d2; bi = i2; }
        }
        if (tx == 0) {
            out_idx[row] = (float)bi;
            const float4* qg = (const float4*)(cw + bi * DDIM);
            float4* og = (float4*)(out_q + row * DDIM);
            float ls = 0.f;
            #pragma unroll
            for (int t = 0; t < 16; ++t) {
                float4 q = qg[t];
                og[t] = q;
                float d0 = q.x - xr[t].x, d1 = q.y - xr[t].y;
                float d2_ = q.z - xr[t].z, d3 = q.w - xr[t].w;
                ls += d0 * d0 + d1 * d1 + d2_ * d2_ + d3 * d3;
            }
            atomicAdd(out_loss, ls * LOSS_SCALE);
        }
    }
}

extern "C" void kernel_launch(void* const* d_in, const int* in_sizes, int n_in,
                              void* d_out, int out_size, void* d_ws, size_t ws_size,
                              hipStream_t stream) {
    const float* x  = (const float*)d_in[0];   // (64,4096,64) fp32
    const float* cw = (const float*)d_in[1];   // (512,64) fp32
    float* out      = (float*)d_out;
    float* out_q    = out;                      // 16777216
    float* out_idx  = out + 16777216;           // 262144
    float* out_loss = out + 16777216 + 262144;  // 1

    char* ws = (char*)d_ws;
    float*     csq   = (float*)(ws + WS_CSQ);
    float*     csqh  = (float*)(ws + WS_CSQH);
    unsigned*  ctr   = (unsigned*)(ws + WS_CTR);
    _Float16*  cw_hl = (_Float16*)(ws + WS_HL);
    int*       list  = (int*)(ws + WS_LIST);

    prep_kernel<<<8, 64, 0, stream>>>(cw, csq, csqh, cw_hl, ctr, out_loss);
    vq_mfma_kernel<<<NVEC / 256, 256, 0, stream>>>(x, cw, cw_hl, csqh, ctr, list,
                                                   out_q, out_idx, out_loss);
    fixup_kernel<<<FIX_BLOCKS, 256, 0, stream>>>(x, cw, csq, ctr, list,
                                                 out_q, out_idx, out_loss);
}

// Round 10
// 279.263 us; speedup vs baseline: 1.8525x; 1.0935x over previous
//
#include <hip/hip_runtime.h>

// VQ: N=262144 vectors (64x4096), D=64, K=512 codewords, fp32.
// out (float32): quantized[16777216] | indices[262144] (as float) | loss[1]
//
// R10 = R9 with the two measured problems fixed:
//  - SPILL (WRITE 183 vs 67 MB, VGPR=80): per-wave row-tiles 4 -> 2, halving
//    long-lived regs (a-frags 32 + m1/m2/idx 24 ~= 56; total ~110). Blocks
//    now cover 128 rows; grid 2048.
//  - FIXUP (~150 us, ~5% flagged at margin 0.015, 6-deep serial rows):
//    DMARGIN 0.005 (>=10x the ~5e-4 worst-case fp16-split error) and
//    FIX_BLOCKS 512 -> all flagged rows run concurrently (wall ~ one row's
//    latency); launch_bounds(256,4) keeps fixup's 64-reg xr unspilled.
// Verified-correct conventions (R8/R9 absmax 0):
//   A-frag: A[m=lane&15][k=quad*8+j]; B-frag: B[n=lane&15][k=quad*8+j];
//   C/D:    col=lane&15, row=quad*4+reg.

typedef _Float16 half8 __attribute__((ext_vector_type(8)));
typedef float    floatx4 __attribute__((ext_vector_type(4)));

#define NVEC  262144
#define DDIM  64
#define KCW   512
#define LOSS_SCALE (0.25f / 16777216.0f)
#define DMARGIN 0.005f
#define FIX_BLOCKS 512

// d_ws layout (re-poisoned 0xAA every call -> prep rewrites everything):
#define WS_CSQ   0          // f32[512]
#define WS_CSQH  2048       // f32[512]  (0.5*csq)
#define WS_CTR   4096       // unsigned[1]
#define WS_HL    8192       // f16[512*128]: row n = hi[64] | lo[64] (256 B)
#define WS_LIST  139264     // int[61440]
#define LIST_CAP 61440

__global__ void prep_kernel(const float* __restrict__ cw,
                            float* __restrict__ csq,
                            float* __restrict__ csqh,
                            _Float16* __restrict__ cw_hl,
                            unsigned* __restrict__ ctr,
                            float* __restrict__ loss_slot) {
    int n = blockIdx.x * blockDim.x + threadIdx.x;
    if (n < KCW) {
        const float4* r = (const float4*)(cw + n * DDIM);
        _Float16* orow = cw_hl + n * 128;
        float s = 0.f;
        #pragma unroll
        for (int t = 0; t < 8; ++t) {
            float4 a = r[2 * t], b = r[2 * t + 1];
            half8 hh, ll;
            #pragma unroll
            for (int i = 0; i < 4; ++i) {
                float v = ((const float*)&a)[i];
                s += v * v;
                _Float16 h = (_Float16)v;
                hh[i] = h; ll[i] = (_Float16)(v - (float)h);
                v = ((const float*)&b)[i];
                s += v * v;
                h = (_Float16)v;
                hh[4 + i] = h; ll[4 + i] = (_Float16)(v - (float)h);
            }
            *(half8*)(orow + 8 * t) = hh;
            *(half8*)(orow + 64 + 8 * t) = ll;
        }
        csq[n]  = s;
        csqh[n] = 0.5f * s;
    }
    if (n == 0) { *loss_slot = 0.f; *ctr = 0u; }
}

__global__ void vq_mfma_kernel(const float* __restrict__ x,
                               const float* __restrict__ cw,
                               const _Float16* __restrict__ cw_hl,
                               const float* __restrict__ csqh,
                               unsigned* __restrict__ ctr, int* __restrict__ list,
                               float* __restrict__ out_q,
                               float* __restrict__ out_idx,
                               float* __restrict__ out_loss) {
    __shared__ _Float16 Bs[128 * 136];   // 34 KB: [n_local][hi64|lo64], pad 136
    __shared__ float csqhs[KCW];         // 2 KB
    __shared__ int   win[128];
    __shared__ unsigned char flg[128];
    __shared__ float red[4];

    const int tid  = threadIdx.x;
    const int w    = tid >> 6;
    const int lane = tid & 63;
    const int quad = lane >> 4;
    const int col  = lane & 15;
    const long blk   = (long)blockIdx.x * 128;
    const long wbase = blk + w * 32;     // wave covers rows wbase..wbase+31

    csqhs[tid]       = csqh[tid];
    csqhs[tid + 256] = csqh[tid + 256];

    // ---- a-frags: 2 row-tiles, hi/lo split, register-resident (32 VGPRs) ----
    half8 ah0[2], ah1[2], al0[2], al1[2];
    #pragma unroll
    for (int rt = 0; rt < 2; ++rt) {
        const float* xr = x + (wbase + rt * 16 + col) * DDIM;
        float4 f0 = *(const float4*)(xr + quad * 8);
        float4 f1 = *(const float4*)(xr + quad * 8 + 4);
        float4 g0 = *(const float4*)(xr + 32 + quad * 8);
        float4 g1 = *(const float4*)(xr + 32 + quad * 8 + 4);
        #pragma unroll
        for (int i = 0; i < 4; ++i) {
            float v = ((const float*)&f0)[i];
            _Float16 h = (_Float16)v;
            ah0[rt][i] = h; al0[rt][i] = (_Float16)(v - (float)h);
            v = ((const float*)&f1)[i]; h = (_Float16)v;
            ah0[rt][4 + i] = h; al0[rt][4 + i] = (_Float16)(v - (float)h);
            v = ((const float*)&g0)[i]; h = (_Float16)v;
            ah1[rt][i] = h; al1[rt][i] = (_Float16)(v - (float)h);
            v = ((const float*)&g1)[i]; h = (_Float16)v;
            ah1[rt][4 + i] = h; al1[rt][4 + i] = (_Float16)(v - (float)h);
        }
    }

    float m1[8], m2[8];
    int   idx[8];
    #pragma unroll
    for (int s = 0; s < 8; ++s) {
        m1[s] = 3.402823466e38f; m2[s] = 3.402823466e38f; idx[s] = 0;
    }

    for (int ch = 0; ch < 4; ++ch) {
        __syncthreads();   // prior chunk consumed (first iter: covers csqhs)
        // ---- stage pre-split chunk: 32 KB, plain copy ----
        {
            int nl = tid >> 1, h = tid & 1;
            const half8* g = (const half8*)(cw_hl + ((ch * 128 + nl) << 7) + (h << 6));
            half8* dst = (half8*)&Bs[nl * 136 + h * 64];
            #pragma unroll
            for (int b = 0; b < 8; ++b) dst[b] = g[b];
        }
        __syncthreads();

        for (int t = 0; t < 8; ++t) {
            const int n  = ch * 128 + t * 16 + col;
            const int nb = (t * 16 + col) * 136;
            half8 bh0 = *(const half8*)&Bs[nb + quad * 8];
            half8 bh1 = *(const half8*)&Bs[nb + 32 + quad * 8];
            half8 bl0 = *(const half8*)&Bs[nb + 64 + quad * 8];
            half8 bl1 = *(const half8*)&Bs[nb + 96 + quad * 8];
            const float vh = csqhs[n];

            #pragma unroll
            for (int rt = 0; rt < 2; ++rt) {
                floatx4 acc = {0.f, 0.f, 0.f, 0.f};
                acc = __builtin_amdgcn_mfma_f32_16x16x32_f16(ah0[rt], bh0, acc, 0, 0, 0);
                acc = __builtin_amdgcn_mfma_f32_16x16x32_f16(ah1[rt], bh1, acc, 0, 0, 0);
                acc = __builtin_amdgcn_mfma_f32_16x16x32_f16(al0[rt], bh0, acc, 0, 0, 0);
                acc = __builtin_amdgcn_mfma_f32_16x16x32_f16(al1[rt], bh1, acc, 0, 0, 0);
                acc = __builtin_amdgcn_mfma_f32_16x16x32_f16(ah0[rt], bl0, acc, 0, 0, 0);
                acc = __builtin_amdgcn_mfma_f32_16x16x32_f16(ah1[rt], bl1, acc, 0, 0, 0);
                #pragma unroll
                for (int reg = 0; reg < 4; ++reg) {
                    int s = rt * 4 + reg;
                    float v = vh - acc[reg];          // (dist - xsq)/2, monotone
                    if (v < m1[s]) idx[s] = n;        // strict < : first-min kept
                    float mx = fmaxf(m1[s], v);
                    m1[s] = fminf(m1[s], v);
                    m2[s] = fminf(m2[s], mx);
                }
            }
        }
    }

    // ---- cross-lane (m1, idx, m2) reduce over the 16 cols of each quad ----
    #pragma unroll
    for (int off = 1; off < 16; off <<= 1) {
        #pragma unroll
        for (int s = 0; s < 8; ++s) {
            float o1 = __shfl_xor(m1[s], off, 16);
            float o2 = __shfl_xor(m2[s], off, 16);
            int   oi = __shfl_xor(idx[s], off, 16);
            float mx = fmaxf(m1[s], o1);
            m2[s] = fminf(fminf(m2[s], o2), mx);
            if (o1 < m1[s] || (o1 == m1[s] && oi < idx[s])) idx[s] = oi;
            m1[s] = fminf(m1[s], o1);
        }
    }

    if (col < 4) {   // lane col handles reg=col for both row-tiles
        #pragma unroll
        for (int rt = 0; rt < 2; ++rt) {
            int s = rt * 4 + col;
            int n_win = idx[s];
            int f = (m2[s] - m1[s] <= DMARGIN) ? 1 : 0;
            long row = wbase + rt * 16 + quad * 4 + col;
            int rl = (int)(row - blk);
            win[rl] = n_win;
            flg[rl] = (unsigned char)f;
            out_idx[row] = (float)n_win;
            if (f) {
                unsigned slot = atomicAdd(ctr, 1u);
                if (slot < LIST_CAP) list[slot] = (int)row;
            }
        }
    }
    __syncthreads();

    // ---- quantized write + commitment loss (flagged rows' loss -> fixup) ----
    float ls = 0.f;
    {
        int m = tid >> 1, h = tid & 1;
        int wn = win[m];
        int f  = flg[m];
        const float4* qg = (const float4*)(cw + wn * DDIM + h * 32);  // L2-hot
        const float4* xg = (const float4*)(x + (blk + m) * DDIM + h * 32);
        float4* og = (float4*)(out_q + (blk + m) * DDIM + h * 32);
        #pragma unroll
        for (int t = 0; t < 8; ++t) {
            float4 q = qg[t];
            float4 xv = xg[t];
            og[t] = q;
            if (!f) {
                float d0 = q.x - xv.x, d1 = q.y - xv.y;
                float d2 = q.z - xv.z, d3 = q.w - xv.w;
                ls += d0 * d0 + d1 * d1 + d2 * d2 + d3 * d3;
            }
        }
    }
    #pragma unroll
    for (int off = 32; off > 0; off >>= 1) ls += __shfl_down(ls, off, 64);
    if ((tid & 63) == 0) red[tid >> 6] = ls;
    __syncthreads();
    if (tid == 0)
        atomicAdd(out_loss, ((red[0] + red[1]) + (red[2] + red[3])) * LOSS_SCALE);
}

// Exact fp32 rescan over the DENSE flagged-row list. 512 blocks x 16 groups
// = 8192 groups >= expected flagged count -> rows run concurrently.
__global__ __launch_bounds__(256, 4)
void fixup_kernel(const float* __restrict__ x, const float* __restrict__ cw,
                  const float* __restrict__ csq,
                  const unsigned* __restrict__ ctr, const int* __restrict__ list,
                  float* __restrict__ out_q, float* __restrict__ out_idx,
                  float* __restrict__ out_loss) {
    const int tid = threadIdx.x;
    const int grp = tid >> 4;
    const int tx  = tid & 15;
    const int gid = blockIdx.x * 16 + grp;
    unsigned cnt = *ctr;
    const int count = (int)(cnt < LIST_CAP ? cnt : LIST_CAP);

    for (int i = gid; i < count; i += 16 * FIX_BLOCKS) {
        long row = (long)list[i];

        float4 xr[16];
        const float4* xg = (const float4*)(x + row * DDIM);
        #pragma unroll
        for (int t = 0; t < 16; ++t) xr[t] = xg[t];

        float best = 3.402823466e38f; int bi = 0;
        for (int j = 0; j < 32; ++j) {
            int n = tx + 16 * j;                 // ascending per lane
            const float4* c = (const float4*)(cw + n * DDIM);
            float a0 = 0.f, a1 = 0.f, a2 = 0.f, a3 = 0.f;
            #pragma unroll
            for (int t = 0; t < 16; ++t) {
                float4 cv = c[t];
                a0 = __builtin_fmaf(xr[t].x, cv.x, a0);
                a1 = __builtin_fmaf(xr[t].y, cv.y, a1);
                a2 = __builtin_fmaf(xr[t].z, cv.z, a2);
                a3 = __builtin_fmaf(xr[t].w, cv.w, a3);
            }
            float sc = __builtin_fmaf(-2.f, (a0 + a1) + (a2 + a3), csq[n]);
            if (sc < best) { best = sc; bi = n; }
        }
        #pragma unroll
        for (int off = 8; off > 0; off >>= 1) {
            float d2 = __shfl_down(best, off, 16);
            int   i2 = __shfl_down(bi,   off, 16);
            if (d2 < best || (d2 == best && i2 < bi)) { best = d2; bi = i2; }
        }
        if (tx == 0) {
            out_idx[row] = (float)bi;
            const float4* qg = (const float4*)(cw + bi * DDIM);
            float4* og = (float4*)(out_q + row * DDIM);
            float ls = 0.f;
            #pragma unroll
            for (int t = 0; t < 16; ++t) {
                float4 q = qg[t];
                og[t] = q;
                float d0 = q.x - xr[t].x, d1 = q.y - xr[t].y;
                float d2_ = q.z - xr[t].z, d3 = q.w - xr[t].w;
                ls += d0 * d0 + d1 * d1 + d2_ * d2_ + d3 * d3;
            }
            atomicAdd(out_loss, ls * LOSS_SCALE);
        }
    }
}

extern "C" void kernel_launch(void* const* d_in, const int* in_sizes, int n_in,
                              void* d_out, int out_size, void* d_ws, size_t ws_size,
                              hipStream_t stream) {
    const float* x  = (const float*)d_in[0];   // (64,4096,64) fp32
    const float* cw = (const float*)d_in[1];   // (512,64) fp32
    float* out      = (float*)d_out;
    float* out_q    = out;                      // 16777216
    float* out_idx  = out + 16777216;           // 262144
    float* out_loss = out + 16777216 + 262144;  // 1

    char* ws = (char*)d_ws;
    float*     csq   = (float*)(ws + WS_CSQ);
    float*     csqh  = (float*)(ws + WS_CSQH);
    unsigned*  ctr   = (unsigned*)(ws + WS_CTR);
    _Float16*  cw_hl = (_Float16*)(ws + WS_HL);
    int*       list  = (int*)(ws + WS_LIST);

    prep_kernel<<<8, 64, 0, stream>>>(cw, csq, csqh, cw_hl, ctr, out_loss);
    vq_mfma_kernel<<<NVEC / 128, 256, 0, stream>>>(x, cw, cw_hl, csqh, ctr, list,
                                                   out_q, out_idx, out_loss);
    fixup_kernel<<<FIX_BLOCKS, 256, 0, stream>>>(x, cw, csq, ctr, list,
                                                 out_q, out_idx, out_loss);
}